// Round 1
// baseline (241.397 us; speedup 1.0000x reference)
//
#include <hip/hip_runtime.h>
#include <math.h>

#define B_ 32
#define K_ 17
#define H_ 128
#define W_ 128
#define HW_ (H_ * W_)            // 16384
#define C_PAF_ 38
#define NE_ 19
#define HM_BLOCKS (B_ * K_)      // 544
#define PAF_BLOCKS 2048
#define THREADS 256
#define PAF_N ((size_t)B_ * C_PAF_ * H_ * W_)   // 19922944
#define PAF_N4 (PAF_N / 4)                      // 4980736

__constant__ int c_edge_a[NE_] = {15,13,16,14,11, 5, 6, 5, 5, 6, 7, 8, 1, 0, 0, 1, 2, 3, 4};
__constant__ int c_edge_b[NE_] = {13,11,14,12,12,11,12, 6, 7, 8, 9,10, 2, 1, 2, 3, 4, 5, 6};

// Blocks [0, 544): per-(b,k) heatmap MSE + argmax (first occurrence).
// Blocks [544, 544+2048): grid-stride partial sums of (paf_pred - paf_gt)^2.
__global__ __launch_bounds__(THREADS) void pose_reduce_kernel(
    const float* __restrict__ hm_pred, const float* __restrict__ hm_gt,
    const float* __restrict__ paf_pred, const float* __restrict__ paf_gt,
    float* __restrict__ per_kp, int* __restrict__ amax,
    float* __restrict__ paf_partial)
{
    __shared__ float s_val[4];
    __shared__ float s_ssq[4];
    __shared__ int   s_idx[4];

    const int t = threadIdx.x;
    const int bid = blockIdx.x;
    const int wave = t >> 6;
    const int lane = t & 63;

    if (bid < HM_BLOCKS) {
        const float4* __restrict__ p = (const float4*)(hm_pred + (size_t)bid * HW_);
        const float4* __restrict__ g = (const float4*)(hm_gt   + (size_t)bid * HW_);
        float ssq = 0.0f;
        float m = -INFINITY;
        int mi = 0;
        #pragma unroll
        for (int i = 0; i < HW_ / 4 / THREADS; ++i) {   // 16 iters
            const int v = t + i * THREADS;
            const float4 a = p[v];
            const float4 b = g[v];
            const float d0 = a.x - b.x, d1 = a.y - b.y, d2 = a.z - b.z, d3 = a.w - b.w;
            ssq += d0 * d0 + d1 * d1 + d2 * d2 + d3 * d3;
            const int base = 4 * v;
            if (a.x > m) { m = a.x; mi = base;     }
            if (a.y > m) { m = a.y; mi = base + 1; }
            if (a.z > m) { m = a.z; mi = base + 2; }
            if (a.w > m) { m = a.w; mi = base + 3; }
        }
        // wave (64-lane) reduction: sum ssq, first-occurrence argmax
        #pragma unroll
        for (int off = 32; off > 0; off >>= 1) {
            const float m2  = __shfl_down(m,   off);
            const int   mi2 = __shfl_down(mi,  off);
            const float s2  = __shfl_down(ssq, off);
            ssq += s2;
            if (m2 > m || (m2 == m && mi2 < mi)) { m = m2; mi = mi2; }
        }
        if (lane == 0) { s_val[wave] = m; s_idx[wave] = mi; s_ssq[wave] = ssq; }
        __syncthreads();
        if (t == 0) {
            #pragma unroll
            for (int wv = 1; wv < 4; ++wv) {
                ssq += s_ssq[wv];
                if (s_val[wv] > m || (s_val[wv] == m && s_idx[wv] < mi)) {
                    m = s_val[wv]; mi = s_idx[wv];
                }
            }
            per_kp[bid] = ssq * (1.0f / (float)HW_);
            amax[bid] = mi;
        }
    } else {
        const int pb = bid - HM_BLOCKS;
        const float4* __restrict__ p = (const float4*)paf_pred;
        const float4* __restrict__ g = (const float4*)paf_gt;
        float ssq = 0.0f;
        for (size_t i = (size_t)pb * THREADS + t; i < PAF_N4; i += (size_t)PAF_BLOCKS * THREADS) {
            const float4 a = p[i];
            const float4 b = g[i];
            const float d0 = a.x - b.x, d1 = a.y - b.y, d2 = a.z - b.z, d3 = a.w - b.w;
            ssq += d0 * d0 + d1 * d1 + d2 * d2 + d3 * d3;
        }
        #pragma unroll
        for (int off = 32; off > 0; off >>= 1) ssq += __shfl_down(ssq, off);
        if (lane == 0) s_ssq[wave] = ssq;
        __syncthreads();
        if (t == 0) paf_partial[pb] = s_ssq[0] + s_ssq[1] + s_ssq[2] + s_ssq[3];
    }
}

__global__ __launch_bounds__(THREADS) void pose_final_kernel(
    const float* __restrict__ per_kp, const int* __restrict__ amax,
    const float* __restrict__ paf_partial, const int* __restrict__ coords,
    float* __restrict__ out)
{
    __shared__ float s_p[4];
    const int t = threadIdx.x;
    const int wave = t >> 6;
    const int lane = t & 63;

    // --- sum paf partials ---
    float ps = 0.0f;
    for (int i = t; i < PAF_BLOCKS; i += THREADS) ps += paf_partial[i];
    #pragma unroll
    for (int off = 32; off > 0; off >>= 1) ps += __shfl_down(ps, off);
    if (lane == 0) s_p[wave] = ps;
    __syncthreads();

    // --- per-batch: top-8 of per_kp + skeleton struct loss ---
    float val = 0.0f;
    if (t < B_) {
        const int b = t;
        float lk[K_];
        float px[K_], py[K_];
        #pragma unroll
        for (int k = 0; k < K_; ++k) {
            lk[k] = per_kp[b * K_ + k];
            const int idx = amax[b * K_ + k];
            px[k] = (float)(idx & (W_ - 1));
            py[k] = (float)(idx >> 7);
        }
        float tsum = 0.0f;
        for (int j = 0; j < 8; ++j) {       // top-8 selection (sum only)
            int best = 0; float bv = lk[0];
            for (int k = 1; k < K_; ++k) if (lk[k] > bv) { bv = lk[k]; best = k; }
            tsum += bv;
            lk[best] = -INFINITY;
        }
        float s = 0.0f;
        for (int e = 0; e < NE_; ++e) {
            const int ea = c_edge_a[e], eb = c_edge_b[e];
            const float dx = px[ea] - px[eb];
            const float dy = py[ea] - py[eb];
            const float plen = sqrtf(dx * dx + dy * dy);
            const float gax = (float)coords[(b * K_ + ea) * 2];
            const float gay = (float)coords[(b * K_ + ea) * 2 + 1];
            const float gbx = (float)coords[(b * K_ + eb) * 2];
            const float gby = (float)coords[(b * K_ + eb) * 2 + 1];
            const float gx = gax - gbx, gy = gay - gby;
            const float glen = sqrtf(gx * gx + gy * gy);
            const float d = plen - glen;
            s += d * d;
        }
        val = tsum * (1.0f / 8.0f) + s / (19.0f + 1e-6f);
    }
    // reduce val (nonzero only in lanes 0..31 of wave 0)
    #pragma unroll
    for (int off = 16; off > 0; off >>= 1) val += __shfl_down(val, off);
    if (t == 0) {
        const float paf_sum = s_p[0] + s_p[1] + s_p[2] + s_p[3];
        out[0] = val * (1.0f / (float)B_) + paf_sum * (1.0f / (float)PAF_N);
    }
}

extern "C" void kernel_launch(void* const* d_in, const int* in_sizes, int n_in,
                              void* d_out, int out_size, void* d_ws, size_t ws_size,
                              hipStream_t stream) {
    const float* hm_pred  = (const float*)d_in[0];
    const float* paf_pred = (const float*)d_in[1];
    const float* hm_gt    = (const float*)d_in[2];
    const float* paf_gt   = (const float*)d_in[3];
    const int*   coords   = (const int*)d_in[4];
    float* out = (float*)d_out;

    float* per_kp      = (float*)d_ws;
    int*   amax        = (int*)((char*)d_ws + HM_BLOCKS * sizeof(float));
    float* paf_partial = (float*)((char*)d_ws + 2 * HM_BLOCKS * sizeof(float));

    pose_reduce_kernel<<<HM_BLOCKS + PAF_BLOCKS, THREADS, 0, stream>>>(
        hm_pred, hm_gt, paf_pred, paf_gt, per_kp, amax, paf_partial);
    pose_final_kernel<<<1, THREADS, 0, stream>>>(
        per_kp, amax, paf_partial, coords, out);
}

// Round 2
// 237.860 us; speedup vs baseline: 1.0149x; 1.0149x over previous
//
#include <hip/hip_runtime.h>
#include <math.h>

#define B_ 32
#define K_ 17
#define H_ 128
#define W_ 128
#define HW_ (H_ * W_)            // 16384
#define C_PAF_ 38
#define NE_ 19
#define HM_BLOCKS (B_ * K_)      // 544
#define PAF_BLOCKS 1216          // 1216*256*16 == PAF_N4 exactly
#define PAF_ITERS 16
#define THREADS 256
#define PAF_N ((size_t)B_ * C_PAF_ * H_ * W_)   // 19922944
#define PAF_N4 (PAF_N / 4)                      // 4980736

__constant__ int c_edge_a[NE_] = {15,13,16,14,11, 5, 6, 5, 5, 6, 7, 8, 1, 0, 0, 1, 2, 3, 4};
__constant__ int c_edge_b[NE_] = {13,11,14,12,12,11,12, 6, 7, 8, 9,10, 2, 1, 2, 3, 4, 5, 6};

// Blocks [0, 544): per-(b,k) heatmap MSE + argmax (first occurrence).
// Blocks [544, 544+1216): partial sums of (paf_pred - paf_gt)^2, 16 float4/thread.
__global__ __launch_bounds__(THREADS) void pose_reduce_kernel(
    const float* __restrict__ hm_pred, const float* __restrict__ hm_gt,
    const float* __restrict__ paf_pred, const float* __restrict__ paf_gt,
    float* __restrict__ per_kp, int* __restrict__ amax,
    float* __restrict__ paf_partial)
{
    __shared__ float s_val[4];
    __shared__ float s_ssq[4];
    __shared__ int   s_idx[4];

    const int t = threadIdx.x;
    const int bid = blockIdx.x;
    const int wave = t >> 6;
    const int lane = t & 63;

    if (bid < HM_BLOCKS) {
        const float4* __restrict__ p = (const float4*)(hm_pred + (size_t)bid * HW_);
        const float4* __restrict__ g = (const float4*)(hm_gt   + (size_t)bid * HW_);
        // 4 independent accumulation chains for ILP (breaks the serial argmax chain)
        float ssq[4] = {0.0f, 0.0f, 0.0f, 0.0f};
        float m[4]; int mi[4];
        #pragma unroll
        for (int j = 0; j < 4; ++j) { m[j] = -INFINITY; mi[j] = 0; }
        #pragma unroll
        for (int i = 0; i < HW_ / 4 / THREADS; ++i) {   // 16 iters
            const int j = i & 3;
            const int v = t + i * THREADS;
            const float4 a = p[v];
            const float4 b = g[v];
            const float d0 = a.x - b.x, d1 = a.y - b.y, d2 = a.z - b.z, d3 = a.w - b.w;
            ssq[j] += d0 * d0 + d1 * d1 + d2 * d2 + d3 * d3;
            // lane-local first-occurrence max of the 4 components (ILP-friendly)
            float m4 = a.x; int k4 = 0;
            if (a.y > m4) { m4 = a.y; k4 = 1; }
            if (a.z > m4) { m4 = a.z; k4 = 2; }
            if (a.w > m4) { m4 = a.w; k4 = 3; }
            if (m4 > m[j]) { m[j] = m4; mi[j] = 4 * v + k4; }
        }
        float sT = (ssq[0] + ssq[1]) + (ssq[2] + ssq[3]);
        float M = m[0]; int MI = mi[0];
        #pragma unroll
        for (int j = 1; j < 4; ++j)
            if (m[j] > M || (m[j] == M && mi[j] < MI)) { M = m[j]; MI = mi[j]; }
        // wave (64-lane) reduction: sum ssq, first-occurrence argmax
        #pragma unroll
        for (int off = 32; off > 0; off >>= 1) {
            const float m2  = __shfl_down(M,  off);
            const int   mi2 = __shfl_down(MI, off);
            const float s2  = __shfl_down(sT, off);
            sT += s2;
            if (m2 > M || (m2 == M && mi2 < MI)) { M = m2; MI = mi2; }
        }
        if (lane == 0) { s_val[wave] = M; s_idx[wave] = MI; s_ssq[wave] = sT; }
        __syncthreads();
        if (t == 0) {
            #pragma unroll
            for (int wv = 1; wv < 4; ++wv) {
                sT += s_ssq[wv];
                if (s_val[wv] > M || (s_val[wv] == M && s_idx[wv] < MI)) {
                    M = s_val[wv]; MI = s_idx[wv];
                }
            }
            per_kp[bid] = sT * (1.0f / (float)HW_);
            amax[bid] = MI;
        }
    } else {
        const int pb = bid - HM_BLOCKS;
        const float4* __restrict__ p = (const float4*)paf_pred;
        const float4* __restrict__ g = (const float4*)paf_gt;
        const size_t base = (size_t)pb * THREADS + t;
        const size_t stride = (size_t)PAF_BLOCKS * THREADS;   // 311296
        float ssq[4] = {0.0f, 0.0f, 0.0f, 0.0f};
        #pragma unroll
        for (int i = 0; i < PAF_ITERS; ++i) {                 // exact cover, no bounds check
            const size_t idx = base + (size_t)i * stride;
            const float4 a = p[idx];
            const float4 b = g[idx];
            const float d0 = a.x - b.x, d1 = a.y - b.y, d2 = a.z - b.z, d3 = a.w - b.w;
            ssq[i & 3] += d0 * d0 + d1 * d1 + d2 * d2 + d3 * d3;
        }
        float sT = (ssq[0] + ssq[1]) + (ssq[2] + ssq[3]);
        #pragma unroll
        for (int off = 32; off > 0; off >>= 1) sT += __shfl_down(sT, off);
        if (lane == 0) s_ssq[wave] = sT;
        __syncthreads();
        if (t == 0) paf_partial[pb] = (s_ssq[0] + s_ssq[1]) + (s_ssq[2] + s_ssq[3]);
    }
}

__global__ __launch_bounds__(THREADS) void pose_final_kernel(
    const float* __restrict__ per_kp, const int* __restrict__ amax,
    const float* __restrict__ paf_partial, const int* __restrict__ coords,
    float* __restrict__ out)
{
    __shared__ float s_p[4];
    const int t = threadIdx.x;
    const int wave = t >> 6;
    const int lane = t & 63;

    // --- sum paf partials ---
    float ps = 0.0f;
    for (int i = t; i < PAF_BLOCKS; i += THREADS) ps += paf_partial[i];
    #pragma unroll
    for (int off = 32; off > 0; off >>= 1) ps += __shfl_down(ps, off);
    if (lane == 0) s_p[wave] = ps;
    __syncthreads();

    // --- per-batch: top-8 of per_kp + skeleton struct loss ---
    float val = 0.0f;
    if (t < B_) {
        const int b = t;
        float lk[K_];
        float px[K_], py[K_];
        #pragma unroll
        for (int k = 0; k < K_; ++k) {
            lk[k] = per_kp[b * K_ + k];
            const int idx = amax[b * K_ + k];
            px[k] = (float)(idx & (W_ - 1));
            py[k] = (float)(idx >> 7);
        }
        float tsum = 0.0f;
        for (int j = 0; j < 8; ++j) {       // top-8 selection (sum only)
            int best = 0; float bv = lk[0];
            for (int k = 1; k < K_; ++k) if (lk[k] > bv) { bv = lk[k]; best = k; }
            tsum += bv;
            lk[best] = -INFINITY;
        }
        float s = 0.0f;
        for (int e = 0; e < NE_; ++e) {
            const int ea = c_edge_a[e], eb = c_edge_b[e];
            const float dx = px[ea] - px[eb];
            const float dy = py[ea] - py[eb];
            const float plen = sqrtf(dx * dx + dy * dy);
            const float gax = (float)coords[(b * K_ + ea) * 2];
            const float gay = (float)coords[(b * K_ + ea) * 2 + 1];
            const float gbx = (float)coords[(b * K_ + eb) * 2];
            const float gby = (float)coords[(b * K_ + eb) * 2 + 1];
            const float gx = gax - gbx, gy = gay - gby;
            const float glen = sqrtf(gx * gx + gy * gy);
            const float d = plen - glen;
            s += d * d;
        }
        val = tsum * (1.0f / 8.0f) + s / (19.0f + 1e-6f);
    }
    // reduce val (nonzero only in lanes 0..31 of wave 0)
    #pragma unroll
    for (int off = 16; off > 0; off >>= 1) val += __shfl_down(val, off);
    if (t == 0) {
        const float paf_sum = s_p[0] + s_p[1] + s_p[2] + s_p[3];
        out[0] = val * (1.0f / (float)B_) + paf_sum * (1.0f / (float)PAF_N);
    }
}

extern "C" void kernel_launch(void* const* d_in, const int* in_sizes, int n_in,
                              void* d_out, int out_size, void* d_ws, size_t ws_size,
                              hipStream_t stream) {
    const float* hm_pred  = (const float*)d_in[0];
    const float* paf_pred = (const float*)d_in[1];
    const float* hm_gt    = (const float*)d_in[2];
    const float* paf_gt   = (const float*)d_in[3];
    const int*   coords   = (const int*)d_in[4];
    float* out = (float*)d_out;

    float* per_kp      = (float*)d_ws;
    int*   amax        = (int*)((char*)d_ws + HM_BLOCKS * sizeof(float));
    float* paf_partial = (float*)((char*)d_ws + 2 * HM_BLOCKS * sizeof(float));

    pose_reduce_kernel<<<HM_BLOCKS + PAF_BLOCKS, THREADS, 0, stream>>>(
        hm_pred, hm_gt, paf_pred, paf_gt, per_kp, amax, paf_partial);
    pose_final_kernel<<<1, THREADS, 0, stream>>>(
        per_kp, amax, paf_partial, coords, out);
}

// Round 3
// 237.683 us; speedup vs baseline: 1.0156x; 1.0007x over previous
//
#include <hip/hip_runtime.h>
#include <math.h>

#define B_ 32
#define K_ 17
#define H_ 128
#define W_ 128
#define HW_ (H_ * W_)            // 16384
#define C_PAF_ 38
#define NE_ 19
#define HM_BLOCKS (B_ * K_)      // 544
#define PAF_BLOCKS 1216          // 1216*256*16 == PAF_N4 exactly
#define THREADS 256
#define PAF_N ((size_t)B_ * C_PAF_ * H_ * W_)   // 19922944
#define PAF_N4 (PAF_N / 4)                      // 4980736

__constant__ int c_edge_a[NE_] = {15,13,16,14,11, 5, 6, 5, 5, 6, 7, 8, 1, 0, 0, 1, 2, 3, 4};
__constant__ int c_edge_b[NE_] = {13,11,14,12,12,11,12, 6, 7, 8, 9,10, 2, 1, 2, 3, 4, 5, 6};

// Blocks [0, 544): per-(b,k) heatmap MSE + argmax (first occurrence).
// Blocks [544, 544+1216): partial sums of (paf_pred - paf_gt)^2, 16 float4/thread.
// Every block streams exactly 128 KB.
__global__ __launch_bounds__(THREADS, 4) void pose_reduce_kernel(
    const float* __restrict__ hm_pred, const float* __restrict__ hm_gt,
    const float* __restrict__ paf_pred, const float* __restrict__ paf_gt,
    float* __restrict__ per_kp, int* __restrict__ amax,
    float* __restrict__ paf_partial)
{
    __shared__ float s_val[4];
    __shared__ float s_ssq[4];
    __shared__ int   s_idx[4];

    const int t = threadIdx.x;
    const int bid = blockIdx.x;
    const int wave = t >> 6;
    const int lane = t & 63;

    if (bid < HM_BLOCKS) {
        const float4* __restrict__ p = (const float4*)(hm_pred + (size_t)bid * HW_);
        const float4* __restrict__ g = (const float4*)(hm_gt   + (size_t)bid * HW_);
        float ssq[4] = {0.0f, 0.0f, 0.0f, 0.0f};
        float m[4]; int mi[4];
        #pragma unroll
        for (int j = 0; j < 4; ++j) { m[j] = -INFINITY; mi[j] = 0; }
        #pragma unroll
        for (int ob = 0; ob < 4; ++ob) {          // 4 batches of 4 float4-pairs
            float4 a[4], b[4];
            #pragma unroll
            for (int j = 0; j < 4; ++j) {         // 8 loads issued back-to-back
                const int v = t + (ob * 4 + j) * THREADS;
                a[j] = p[v];
                b[j] = g[v];
            }
            #pragma unroll
            for (int j = 0; j < 4; ++j) {
                const int v = t + (ob * 4 + j) * THREADS;
                const float d0 = a[j].x - b[j].x, d1 = a[j].y - b[j].y;
                const float d2 = a[j].z - b[j].z, d3 = a[j].w - b[j].w;
                ssq[j] += d0 * d0 + d1 * d1 + d2 * d2 + d3 * d3;
                // lane-local first-occurrence max of the 4 components
                float m4 = a[j].x; int k4 = 0;
                if (a[j].y > m4) { m4 = a[j].y; k4 = 1; }
                if (a[j].z > m4) { m4 = a[j].z; k4 = 2; }
                if (a[j].w > m4) { m4 = a[j].w; k4 = 3; }
                if (m4 > m[j]) { m[j] = m4; mi[j] = 4 * v + k4; }
            }
        }
        float sT = (ssq[0] + ssq[1]) + (ssq[2] + ssq[3]);
        float M = m[0]; int MI = mi[0];
        #pragma unroll
        for (int j = 1; j < 4; ++j)
            if (m[j] > M || (m[j] == M && mi[j] < MI)) { M = m[j]; MI = mi[j]; }
        // wave (64-lane) reduction: sum ssq, first-occurrence argmax
        #pragma unroll
        for (int off = 32; off > 0; off >>= 1) {
            const float m2  = __shfl_down(M,  off);
            const int   mi2 = __shfl_down(MI, off);
            const float s2  = __shfl_down(sT, off);
            sT += s2;
            if (m2 > M || (m2 == M && mi2 < MI)) { M = m2; MI = mi2; }
        }
        if (lane == 0) { s_val[wave] = M; s_idx[wave] = MI; s_ssq[wave] = sT; }
        __syncthreads();
        if (t == 0) {
            #pragma unroll
            for (int wv = 1; wv < 4; ++wv) {
                sT += s_ssq[wv];
                if (s_val[wv] > M || (s_val[wv] == M && s_idx[wv] < MI)) {
                    M = s_val[wv]; MI = s_idx[wv];
                }
            }
            per_kp[bid] = sT * (1.0f / (float)HW_);
            amax[bid] = MI;
        }
    } else {
        const int pb = bid - HM_BLOCKS;
        const float4* __restrict__ p = (const float4*)paf_pred;
        const float4* __restrict__ g = (const float4*)paf_gt;
        const size_t base = (size_t)pb * THREADS + t;
        const size_t stride = (size_t)PAF_BLOCKS * THREADS;   // 311296
        float ssq[4] = {0.0f, 0.0f, 0.0f, 0.0f};
        #pragma unroll
        for (int ob = 0; ob < 4; ++ob) {          // 4 batches of 4 float4-pairs
            float4 a[4], b[4];
            #pragma unroll
            for (int j = 0; j < 4; ++j) {         // 8 loads issued back-to-back
                const size_t idx = base + (size_t)(ob * 4 + j) * stride;
                a[j] = p[idx];
                b[j] = g[idx];
            }
            #pragma unroll
            for (int j = 0; j < 4; ++j) {
                const float d0 = a[j].x - b[j].x, d1 = a[j].y - b[j].y;
                const float d2 = a[j].z - b[j].z, d3 = a[j].w - b[j].w;
                ssq[j] += d0 * d0 + d1 * d1 + d2 * d2 + d3 * d3;
            }
        }
        float sT = (ssq[0] + ssq[1]) + (ssq[2] + ssq[3]);
        #pragma unroll
        for (int off = 32; off > 0; off >>= 1) sT += __shfl_down(sT, off);
        if (lane == 0) s_ssq[wave] = sT;
        __syncthreads();
        if (t == 0) paf_partial[pb] = (s_ssq[0] + s_ssq[1]) + (s_ssq[2] + s_ssq[3]);
    }
}

__global__ __launch_bounds__(THREADS) void pose_final_kernel(
    const float* __restrict__ per_kp, const int* __restrict__ amax,
    const float* __restrict__ paf_partial, const int* __restrict__ coords,
    float* __restrict__ out)
{
    __shared__ float s_p[4];
    const int t = threadIdx.x;
    const int wave = t >> 6;
    const int lane = t & 63;

    // --- sum paf partials ---
    float ps = 0.0f;
    for (int i = t; i < PAF_BLOCKS; i += THREADS) ps += paf_partial[i];
    #pragma unroll
    for (int off = 32; off > 0; off >>= 1) ps += __shfl_down(ps, off);
    if (lane == 0) s_p[wave] = ps;
    __syncthreads();

    // --- per-batch: top-8 of per_kp + skeleton struct loss ---
    float val = 0.0f;
    if (t < B_) {
        const int b = t;
        float lk[K_];
        float px[K_], py[K_];
        #pragma unroll
        for (int k = 0; k < K_; ++k) {
            lk[k] = per_kp[b * K_ + k];
            const int idx = amax[b * K_ + k];
            px[k] = (float)(idx & (W_ - 1));
            py[k] = (float)(idx >> 7);
        }
        float tsum = 0.0f;
        for (int j = 0; j < 8; ++j) {       // top-8 selection (sum only)
            int best = 0; float bv = lk[0];
            for (int k = 1; k < K_; ++k) if (lk[k] > bv) { bv = lk[k]; best = k; }
            tsum += bv;
            lk[best] = -INFINITY;
        }
        float s = 0.0f;
        for (int e = 0; e < NE_; ++e) {
            const int ea = c_edge_a[e], eb = c_edge_b[e];
            const float dx = px[ea] - px[eb];
            const float dy = py[ea] - py[eb];
            const float plen = sqrtf(dx * dx + dy * dy);
            const float gax = (float)coords[(b * K_ + ea) * 2];
            const float gay = (float)coords[(b * K_ + ea) * 2 + 1];
            const float gbx = (float)coords[(b * K_ + eb) * 2];
            const float gby = (float)coords[(b * K_ + eb) * 2 + 1];
            const float gx = gax - gbx, gy = gay - gby;
            const float glen = sqrtf(gx * gx + gy * gy);
            const float d = plen - glen;
            s += d * d;
        }
        val = tsum * (1.0f / 8.0f) + s / (19.0f + 1e-6f);
    }
    // reduce val (nonzero only in lanes 0..31 of wave 0)
    #pragma unroll
    for (int off = 16; off > 0; off >>= 1) val += __shfl_down(val, off);
    if (t == 0) {
        const float paf_sum = s_p[0] + s_p[1] + s_p[2] + s_p[3];
        out[0] = val * (1.0f / (float)B_) + paf_sum * (1.0f / (float)PAF_N);
    }
}

extern "C" void kernel_launch(void* const* d_in, const int* in_sizes, int n_in,
                              void* d_out, int out_size, void* d_ws, size_t ws_size,
                              hipStream_t stream) {
    const float* hm_pred  = (const float*)d_in[0];
    const float* paf_pred = (const float*)d_in[1];
    const float* hm_gt    = (const float*)d_in[2];
    const float* paf_gt   = (const float*)d_in[3];
    const int*   coords   = (const int*)d_in[4];
    float* out = (float*)d_out;

    float* per_kp      = (float*)d_ws;
    int*   amax        = (int*)((char*)d_ws + HM_BLOCKS * sizeof(float));
    float* paf_partial = (float*)((char*)d_ws + 2 * HM_BLOCKS * sizeof(float));

    pose_reduce_kernel<<<HM_BLOCKS + PAF_BLOCKS, THREADS, 0, stream>>>(
        hm_pred, hm_gt, paf_pred, paf_gt, per_kp, amax, paf_partial);
    pose_final_kernel<<<1, THREADS, 0, stream>>>(
        per_kp, amax, paf_partial, coords, out);
}

// Round 5
// 213.104 us; speedup vs baseline: 1.1328x; 1.1153x over previous
//
#include <hip/hip_runtime.h>
#include <math.h>

#define B_ 32
#define K_ 17
#define H_ 128
#define W_ 128
#define HW_ (H_ * W_)            // 16384
#define C_PAF_ 38
#define NE_ 19
#define HM_TILES (B_ * K_)       // 544
#define HM_BLOCKS (HM_TILES * 2) // 1088, two half-tiles per (b,k)
#define HM_HALF 8192             // floats per half-tile
#define PAF_BLOCKS 2432          // 2432*2048 == PAF_N4 exactly
#define THREADS 256
#define PAF_N ((size_t)B_ * C_PAF_ * H_ * W_)   // 19922944
#define PAF_N4 (PAF_N / 4)                      // 4980736

typedef float fvec4 __attribute__((ext_vector_type(4)));

__constant__ int c_edge_a[NE_] = {15,13,16,14,11, 5, 6, 5, 5, 6, 7, 8, 1, 0, 0, 1, 2, 3, 4};
__constant__ int c_edge_b[NE_] = {13,11,14,12,12,11,12, 6, 7, 8, 9,10, 2, 1, 2, 3, 4, 5, 6};

// ws layout
#define WS_SSQH 0                                  // float[1088]
#define WS_MH   (HM_BLOCKS)                        // float[1088]
#define WS_MIH  (2 * HM_BLOCKS)                    // int[1088]
#define WS_PAF  (3 * HM_BLOCKS)                    // float[2432]

// Every block streams exactly 64 KB (32 KB from each of two buffers), contiguous.
// Blocks [0, 1088): half-tile heatmap ssq + argmax partials.
// Blocks [1088, 1088+2432): paf ssq partials.
__global__ __launch_bounds__(THREADS, 8) void pose_reduce_kernel(
    const float* __restrict__ hm_pred, const float* __restrict__ hm_gt,
    const float* __restrict__ paf_pred, const float* __restrict__ paf_gt,
    float* __restrict__ ws_f, int* __restrict__ ws_i)
{
    __shared__ float s_val[4];
    __shared__ float s_ssq[4];
    __shared__ int   s_idx[4];

    const int t = threadIdx.x;
    const int bid = blockIdx.x;
    const int wave = t >> 6;
    const int lane = t & 63;

    if (bid < HM_BLOCKS) {
        const int tile = bid >> 1;
        const int half = bid & 1;
        const size_t off = (size_t)tile * HW_ + (size_t)half * HM_HALF;
        const fvec4* __restrict__ p = (const fvec4*)(hm_pred + off);
        const fvec4* __restrict__ g = (const fvec4*)(hm_gt   + off);
        float ssq[2] = {0.0f, 0.0f};
        float m[2] = {-INFINITY, -INFINITY};
        int mi[2] = {0, 0};
        #pragma unroll
        for (int ob = 0; ob < 4; ++ob) {      // 8 float4/thread, batches of 2
            const int v0 = t + (ob * 2 + 0) * THREADS;
            const int v1 = t + (ob * 2 + 1) * THREADS;
            const fvec4 a0 = __builtin_nontemporal_load(p + v0);
            const fvec4 b0 = __builtin_nontemporal_load(g + v0);
            const fvec4 a1 = __builtin_nontemporal_load(p + v1);
            const fvec4 b1 = __builtin_nontemporal_load(g + v1);
            {
                const float d0 = a0.x - b0.x, d1 = a0.y - b0.y;
                const float d2 = a0.z - b0.z, d3 = a0.w - b0.w;
                ssq[0] += d0 * d0 + d1 * d1 + d2 * d2 + d3 * d3;
                float m4 = a0.x; int k4 = 0;
                if (a0.y > m4) { m4 = a0.y; k4 = 1; }
                if (a0.z > m4) { m4 = a0.z; k4 = 2; }
                if (a0.w > m4) { m4 = a0.w; k4 = 3; }
                if (m4 > m[0]) { m[0] = m4; mi[0] = 4 * v0 + k4; }
            }
            {
                const float d0 = a1.x - b1.x, d1 = a1.y - b1.y;
                const float d2 = a1.z - b1.z, d3 = a1.w - b1.w;
                ssq[1] += d0 * d0 + d1 * d1 + d2 * d2 + d3 * d3;
                float m4 = a1.x; int k4 = 0;
                if (a1.y > m4) { m4 = a1.y; k4 = 1; }
                if (a1.z > m4) { m4 = a1.z; k4 = 2; }
                if (a1.w > m4) { m4 = a1.w; k4 = 3; }
                if (m4 > m[1]) { m[1] = m4; mi[1] = 4 * v1 + k4; }
            }
        }
        float sT = ssq[0] + ssq[1];
        float M; int MI;
        if (m[1] > m[0] || (m[1] == m[0] && mi[1] < mi[0])) { M = m[1]; MI = mi[1]; }
        else { M = m[0]; MI = mi[0]; }
        #pragma unroll
        for (int off2 = 32; off2 > 0; off2 >>= 1) {
            const float m2  = __shfl_down(M,  off2);
            const int   mi2 = __shfl_down(MI, off2);
            const float s2  = __shfl_down(sT, off2);
            sT += s2;
            if (m2 > M || (m2 == M && mi2 < MI)) { M = m2; MI = mi2; }
        }
        if (lane == 0) { s_val[wave] = M; s_idx[wave] = MI; s_ssq[wave] = sT; }
        __syncthreads();
        if (t == 0) {
            #pragma unroll
            for (int wv = 1; wv < 4; ++wv) {
                sT += s_ssq[wv];
                if (s_val[wv] > M || (s_val[wv] == M && s_idx[wv] < MI)) {
                    M = s_val[wv]; MI = s_idx[wv];
                }
            }
            ws_f[WS_SSQH + bid] = sT;
            ws_f[WS_MH + bid] = M;
            ws_i[WS_MIH + bid] = half * HM_HALF + MI;  // index within the full tile
        }
    } else {
        const int pb = bid - HM_BLOCKS;
        const fvec4* __restrict__ p = (const fvec4*)paf_pred + (size_t)pb * 2048;
        const fvec4* __restrict__ g = (const fvec4*)paf_gt   + (size_t)pb * 2048;
        float ssq[2] = {0.0f, 0.0f};
        #pragma unroll
        for (int ob = 0; ob < 4; ++ob) {      // 8 float4/thread, batches of 2
            const int v0 = t + (ob * 2 + 0) * THREADS;
            const int v1 = t + (ob * 2 + 1) * THREADS;
            const fvec4 a0 = __builtin_nontemporal_load(p + v0);
            const fvec4 b0 = __builtin_nontemporal_load(g + v0);
            const fvec4 a1 = __builtin_nontemporal_load(p + v1);
            const fvec4 b1 = __builtin_nontemporal_load(g + v1);
            {
                const float d0 = a0.x - b0.x, d1 = a0.y - b0.y;
                const float d2 = a0.z - b0.z, d3 = a0.w - b0.w;
                ssq[0] += d0 * d0 + d1 * d1 + d2 * d2 + d3 * d3;
            }
            {
                const float d0 = a1.x - b1.x, d1 = a1.y - b1.y;
                const float d2 = a1.z - b1.z, d3 = a1.w - b1.w;
                ssq[1] += d0 * d0 + d1 * d1 + d2 * d2 + d3 * d3;
            }
        }
        float sT = ssq[0] + ssq[1];
        #pragma unroll
        for (int off2 = 32; off2 > 0; off2 >>= 1) sT += __shfl_down(sT, off2);
        if (lane == 0) s_ssq[wave] = sT;
        __syncthreads();
        if (t == 0) ws_f[WS_PAF + pb] = (s_ssq[0] + s_ssq[1]) + (s_ssq[2] + s_ssq[3]);
    }
}

__global__ __launch_bounds__(THREADS) void pose_final_kernel(
    const float* __restrict__ ws_f, const int* __restrict__ ws_i,
    const int* __restrict__ coords, float* __restrict__ out)
{
    __shared__ float s_p[4];
    const int t = threadIdx.x;
    const int wave = t >> 6;
    const int lane = t & 63;

    // --- sum paf partials (2432) ---
    float ps = 0.0f;
    for (int i = t; i < PAF_BLOCKS; i += THREADS) ps += ws_f[WS_PAF + i];
    #pragma unroll
    for (int off = 32; off > 0; off >>= 1) ps += __shfl_down(ps, off);
    if (lane == 0) s_p[wave] = ps;
    __syncthreads();

    // --- per-batch: merge half-tiles, top-8, skeleton loss ---
    float val = 0.0f;
    if (t < B_) {
        const int b = t;
        float lk[K_];
        float px[K_], py[K_];
        #pragma unroll
        for (int k = 0; k < K_; ++k) {
            const int j = b * K_ + k;
            const float s0 = ws_f[WS_SSQH + 2 * j], s1 = ws_f[WS_SSQH + 2 * j + 1];
            lk[k] = (s0 + s1) * (1.0f / (float)HW_);
            const float m0 = ws_f[WS_MH + 2 * j], m1 = ws_f[WS_MH + 2 * j + 1];
            // strict >: tie goes to half 0, whose indices are all smaller (first occurrence)
            const int idx = (m1 > m0) ? ws_i[WS_MIH + 2 * j + 1] : ws_i[WS_MIH + 2 * j];
            px[k] = (float)(idx & (W_ - 1));
            py[k] = (float)(idx >> 7);
        }
        float tsum = 0.0f;
        for (int jj = 0; jj < 8; ++jj) {     // top-8 selection (sum only)
            int best = 0; float bv = lk[0];
            for (int k = 1; k < K_; ++k) if (lk[k] > bv) { bv = lk[k]; best = k; }
            tsum += bv;
            lk[best] = -INFINITY;
        }
        float s = 0.0f;
        for (int e = 0; e < NE_; ++e) {
            const int ea = c_edge_a[e], eb = c_edge_b[e];
            const float dx = px[ea] - px[eb];
            const float dy = py[ea] - py[eb];
            const float plen = sqrtf(dx * dx + dy * dy);
            const float gax = (float)coords[(b * K_ + ea) * 2];
            const float gay = (float)coords[(b * K_ + ea) * 2 + 1];
            const float gbx = (float)coords[(b * K_ + eb) * 2];
            const float gby = (float)coords[(b * K_ + eb) * 2 + 1];
            const float gx = gax - gbx, gy = gay - gby;
            const float glen = sqrtf(gx * gx + gy * gy);
            const float d = plen - glen;
            s += d * d;
        }
        val = tsum * (1.0f / 8.0f) + s / (19.0f + 1e-6f);
    }
    #pragma unroll
    for (int off = 16; off > 0; off >>= 1) val += __shfl_down(val, off);
    if (t == 0) {
        const float paf_sum = s_p[0] + s_p[1] + s_p[2] + s_p[3];
        out[0] = val * (1.0f / (float)B_) + paf_sum * (1.0f / (float)PAF_N);
    }
}

extern "C" void kernel_launch(void* const* d_in, const int* in_sizes, int n_in,
                              void* d_out, int out_size, void* d_ws, size_t ws_size,
                              hipStream_t stream) {
    const float* hm_pred  = (const float*)d_in[0];
    const float* paf_pred = (const float*)d_in[1];
    const float* hm_gt    = (const float*)d_in[2];
    const float* paf_gt   = (const float*)d_in[3];
    const int*   coords   = (const int*)d_in[4];
    float* out = (float*)d_out;

    float* ws_f = (float*)d_ws;
    int*   ws_i = (int*)d_ws;   // disjoint index ranges within the same buffer

    pose_reduce_kernel<<<HM_BLOCKS + PAF_BLOCKS, THREADS, 0, stream>>>(
        hm_pred, hm_gt, paf_pred, paf_gt, ws_f, ws_i);
    pose_final_kernel<<<1, THREADS, 0, stream>>>(ws_f, ws_i, coords, out);
}